// Round 7
// baseline (1957.040 us; speedup 1.0000x reference)
//
#include <hip/hip_runtime.h>
#include <math.h>

#define N_NODES 20000
#define E_EDGES 200000
#define M1 60000            // layer-1 node count (3*N)
#define TE 16               // slots (edges) per block in pair/att kernels
#define Z0CAP 80000         // layer-0 z chunk capacity in slots

typedef __attribute__((ext_vector_type(8))) short short8;
typedef __attribute__((ext_vector_type(4))) float f32x4;

// float -> bf16 (round-to-nearest-even), bit-level
__device__ __forceinline__ unsigned short f2bf(float f) {
    union { float f; unsigned int u; } v; v.f = f;
    unsigned int r = v.u + 0x7fffu + ((v.u >> 16) & 1u);
    return (unsigned short)(r >> 16);
}
__device__ __forceinline__ float bf2f(unsigned short u) {
    union { unsigned int u; float f; } v; v.u = ((unsigned int)u) << 16;
    return v.f;
}

// load 8 consecutive fp32 from global, pack to 8 bf16 (one MFMA A-frag slice)
__device__ __forceinline__ short8 ldA(const float* p) {
    float4 f0 = *(const float4*)p;
    float4 f1 = *(const float4*)(p + 4);
    short8 r;
    r[0] = (short)f2bf(f0.x); r[1] = (short)f2bf(f0.y);
    r[2] = (short)f2bf(f0.z); r[3] = (short)f2bf(f0.w);
    r[4] = (short)f2bf(f1.x); r[5] = (short)f2bf(f1.y);
    r[6] = (short)f2bf(f1.z); r[7] = (short)f2bf(f1.w);
    return r;
}

// ---------------------------------------------------------------------------
// GEMM: C[M,256] = X[M,K] @ W[K,256]  (fp32)
// ---------------------------------------------------------------------------
template<int K>
__global__ __launch_bounds__(256) void gemm_proj(const float* __restrict__ X,
                                                 const float* __restrict__ W,
                                                 float* __restrict__ C) {
    __shared__ float Xs[16][K];
    const int row0 = blockIdx.x * 16;
    const int tid = threadIdx.x;
    for (int i4 = tid; i4 < 16 * K / 4; i4 += 256) {
        int r = i4 / (K / 4), kq = i4 - r * (K / 4);
        ((float4*)&Xs[r][0])[kq] = ((const float4*)(X + (size_t)(row0 + r) * K))[kq];
    }
    __syncthreads();
    const int rg = tid >> 6;
    const int j0 = (tid & 63) * 4;
    float acc[4][4];
#pragma unroll
    for (int r = 0; r < 4; ++r)
#pragma unroll
        for (int t = 0; t < 4; ++t) acc[r][t] = 0.f;
#pragma unroll 4
    for (int k = 0; k < K; ++k) {
        float4 wq = *(const float4*)(W + (size_t)k * 256 + j0);
#pragma unroll
        for (int r = 0; r < 4; ++r) {
            float xv = Xs[rg * 4 + r][k];
            acc[r][0] = fmaf(xv, wq.x, acc[r][0]);
            acc[r][1] = fmaf(xv, wq.y, acc[r][1]);
            acc[r][2] = fmaf(xv, wq.z, acc[r][2]);
            acc[r][3] = fmaf(xv, wq.w, acc[r][3]);
        }
    }
#pragma unroll
    for (int r = 0; r < 4; ++r)
        *(float4*)(C + (size_t)(row0 + rg * 4 + r) * 256 + j0) =
            make_float4(acc[r][0], acc[r][1], acc[r][2], acc[r][3]);
}

// ---------------------------------------------------------------------------
// Weight prep: W[K][64] fp32 -> WT[64][K] bf16 (transpose + convert)
// ---------------------------------------------------------------------------
__global__ void prep_wt(const float* __restrict__ W, unsigned short* __restrict__ WT,
                        int K) {
    int i = blockIdx.x * 256 + threadIdx.x;
    if (i >= 64 * K) return;
    int c = i / K, k = i - c * K;
    WT[i] = f2bf(W[k * 64 + c]);
}

// ---------------------------------------------------------------------------
// CSR build: cnt -> scan -> fill  (shared by both layers)
// ---------------------------------------------------------------------------
__global__ void zero_cnt(int* cnt) {
    int i = blockIdx.x * 256 + threadIdx.x;
    if (i < 3 * N_NODES) cnt[i] = 0;
}
__global__ void hist_k(const int* __restrict__ ei, int* __restrict__ cnt) {
    int i = blockIdx.x * 256 + threadIdx.x;
    if (i >= 3 * E_EDGES) return;
    int p = i / E_EDGES;
    atomicAdd(&cnt[p * N_NODES + ei[i]], 1);
}
__global__ __launch_bounds__(1024) void scan_k(const int* __restrict__ cnt,
                                               int* __restrict__ startA,
                                               int* __restrict__ cursor) {
    const int p = blockIdx.x;         // 0..2
    const int t = threadIdx.x;
    const int CH = (N_NODES + 1023) / 1024;  // 20
    int loc[CH];
    int own = 0;
    const int b0 = t * CH;
#pragma unroll
    for (int i = 0; i < CH; ++i) {
        int b = b0 + i;
        int c = (b < N_NODES) ? cnt[p * N_NODES + b] : 0;
        loc[i] = c; own += c;
    }
    __shared__ int sc[1024];
    sc[t] = own;
    __syncthreads();
    for (int off = 1; off < 1024; off <<= 1) {
        int vprev = (t >= off) ? sc[t - off] : 0;
        __syncthreads();
        sc[t] += vprev;
        __syncthreads();
    }
    int base = sc[t] - own;  // exclusive prefix
#pragma unroll
    for (int i = 0; i < CH; ++i) {
        int b = b0 + i;
        if (b < N_NODES) {
            startA[p * (N_NODES + 1) + b] = base;
            cursor[p * N_NODES + b] = base;
            base += loc[i];
        }
    }
    if (t == 1023) startA[p * (N_NODES + 1) + N_NODES] = sc[1023];
}
__global__ void fill_k(const int* __restrict__ ei, int* __restrict__ cursor,
                       int* __restrict__ idxA) {
    int i = blockIdx.x * 256 + threadIdx.x;
    if (i >= 3 * E_EDGES) return;
    int p = i / E_EDGES, e = i - p * E_EDGES;
    int v = ei[i];
    int pos = atomicAdd(&cursor[p * N_NODES + v], 1);
    idxA[p * E_EDGES + pos] = e;
}

// ---------------------------------------------------------------------------
// Pair MLP core: a1 = leaky(concat(A0,A1)@eW1+eb1); a2 = a1@eW2.
// nb: per-wave LDS scratch [16 rows][64 cols] bf16, XOR-chunk-swizzled.
// ---------------------------------------------------------------------------
__device__ __forceinline__ void pair_mlp(const short8 A0[2], const short8 A1[2],
                                         const unsigned short* __restrict__ eW1t,
                                         const unsigned short* __restrict__ eW2t,
                                         const float eb1c[4],
                                         unsigned short* nb,
                                         int g, int t, int ko, f32x4 a2[4]) {
    const f32x4 z = {0.f, 0.f, 0.f, 0.f};
    f32x4 a1[4] = {z, z, z, z};
#pragma unroll
    for (int half = 0; half < 2; ++half) {
#pragma unroll
        for (int ks = 0; ks < 2; ++ks) {
            short8 a = half ? A1[ks] : A0[ks];
#pragma unroll
            for (int f = 0; f < 4; ++f) {
                short8 b = *(const short8*)(eW1t + (16 * f + t) * 128 + half * 64 + ks * 32 + ko);
                a1[f] = __builtin_amdgcn_mfma_f32_16x16x32_bf16(a, b, a1[f], 0, 0, 0);
            }
        }
    }
#pragma unroll
    for (int f = 0; f < 4; ++f) {
        const int col = 16 * f + t;
#pragma unroll
        for (int r = 0; r < 4; ++r) {
            const int row = 4 * g + r;
            float hv = a1[f][r] + eb1c[f];
            hv = (hv >= 0.f) ? hv : 0.2f * hv;
            const int chunk = (col >> 3) ^ (row & 7);
            nb[row * 64 + chunk * 8 + (col & 7)] = f2bf(hv);
        }
    }
#pragma unroll
    for (int f = 0; f < 4; ++f) a2[f] = z;
#pragma unroll
    for (int ks = 0; ks < 2; ++ks) {
        const int chunk = (ks * 4 + g) ^ (t & 7);
        short8 a = *(const short8*)(nb + t * 64 + chunk * 8);
#pragma unroll
        for (int f = 0; f < 4; ++f) {
            short8 b = *(const short8*)(eW2t + (16 * f + t) * 64 + ks * 32 + ko);
            a2[f] = __builtin_amdgcn_mfma_f32_16x16x32_bf16(a, b, a2[f], 0, 0, 0);
        }
    }
}

// ---------------------------------------------------------------------------
// Attention-only kernel: alpha[e] (float4 over heads). Edge order.
// Block: 16 edges, 4 waves; wave = 4 edges = 16 MFMA rows.
// ---------------------------------------------------------------------------
__global__ __launch_bounds__(256) void att_alpha(const float* __restrict__ proj,
                                                 const int* __restrict__ ei,
                                                 const unsigned short* __restrict__ aW1t,
                                                 const float* __restrict__ ab1,
                                                 const float* __restrict__ aW2,
                                                 const float* __restrict__ ab2,
                                                 float4* __restrict__ alphab) {
    const int tid = threadIdx.x;
    const int w = tid >> 6, lane = tid & 63;
    const int g = lane >> 4, t = lane & 15;
    const int e0 = blockIdx.x * TE + w * 4;
    const int ko = g * 8;

    const int ea = e0 + (t >> 2);
    const int head = t & 3;
    const float* baseD = proj + (size_t)ei[ea] * 256 + head * 64;
    const float* baseM = proj + (size_t)ei[E_EDGES + ea] * 256 + head * 64;
    const float* baseS = proj + (size_t)ei[2 * E_EDGES + ea] * 256 + head * 64;

    short8 aD[2], aM[2], aS[2];
#pragma unroll
    for (int ks = 0; ks < 2; ++ks) {
        aD[ks] = ldA(baseD + ks * 32 + ko);
        aM[ks] = ldA(baseM + ks * 32 + ko);
        aS[ks] = ldA(baseS + ks * 32 + ko);
    }

    float ab1c[4], aW2c[4];
#pragma unroll
    for (int f = 0; f < 4; ++f) {
        ab1c[f] = ab1[16 * f + t];
        aW2c[f] = aW2[16 * f + t];
    }

    const f32x4 z = {0.f, 0.f, 0.f, 0.f};
    f32x4 acc[4] = {z, z, z, z};
#pragma unroll
    for (int ks = 0; ks < 2; ++ks) {
        short8 a = aD[ks];
#pragma unroll
        for (int f = 0; f < 4; ++f) {
            short8 b = *(const short8*)(aW1t + (16 * f + t) * 192 + 0 * 64 + ks * 32 + ko);
            acc[f] = __builtin_amdgcn_mfma_f32_16x16x32_bf16(a, b, acc[f], 0, 0, 0);
        }
    }
#pragma unroll
    for (int ks = 0; ks < 2; ++ks) {
        short8 a = aM[ks];
#pragma unroll
        for (int f = 0; f < 4; ++f) {
            short8 b = *(const short8*)(aW1t + (16 * f + t) * 192 + 1 * 64 + ks * 32 + ko);
            acc[f] = __builtin_amdgcn_mfma_f32_16x16x32_bf16(a, b, acc[f], 0, 0, 0);
        }
    }
#pragma unroll
    for (int ks = 0; ks < 2; ++ks) {
        short8 a = aS[ks];
#pragma unroll
        for (int f = 0; f < 4; ++f) {
            short8 b = *(const short8*)(aW1t + (16 * f + t) * 192 + 2 * 64 + ks * 32 + ko);
            acc[f] = __builtin_amdgcn_mfma_f32_16x16x32_bf16(a, b, acc[f], 0, 0, 0);
        }
    }

    // relu, @aW2 (col-reduce), allreduce over t, +ab2, leaky, softmax
    float p_[4];
#pragma unroll
    for (int r = 0; r < 4; ++r) {
        float s = 0.f;
#pragma unroll
        for (int f = 0; f < 4; ++f) {
            float hv = fmaxf(acc[f][r] + ab1c[f], 0.f);
            s = fmaf(hv, aW2c[f], s);
        }
        p_[r] = s;
    }
#pragma unroll
    for (int off = 1; off < 16; off <<= 1) {
#pragma unroll
        for (int r = 0; r < 4; ++r) p_[r] += __shfl_xor(p_[r], off);
    }
    const float b2 = ab2[0];
    float sc[4];
#pragma unroll
    for (int r = 0; r < 4; ++r) {
        float v = p_[r] + b2;
        sc[r] = (v >= 0.f) ? v : 0.2f * v;
    }
    float mx = fmaxf(fmaxf(sc[0], sc[1]), fmaxf(sc[2], sc[3]));
    float ex[4], sum = 0.f;
#pragma unroll
    for (int r = 0; r < 4; ++r) { ex[r] = expf(sc[r] - mx); sum += ex[r]; }
    float inv = 1.f / sum;
    if (t == 0)
        alphab[e0 + g] = make_float4(ex[0] * inv, ex[1] * inv, ex[2] * inv, ex[3] * inv);
}

// ---------------------------------------------------------------------------
// Pair kernel: CSR-slot-ordered. Block = 16 slots, 4 waves x 4 slots.
// Writes z[slot-slotbase] densely (no atomics).
// LAYER0: bf16 256-col rows, lane-permuted pos s=16t+4r+f.
// LAYER1: fp32 64-col rows (head-mean pre-applied), logical layout.
// ---------------------------------------------------------------------------
template<int LAYER>
__global__ __launch_bounds__(256) void pair_k(const float* __restrict__ proj,
                                              const int* __restrict__ ei,
                                              const int* __restrict__ idxA,
                                              const int* __restrict__ startA,
                                              int p, int rA, int rB, int v0, int v1,
                                              const unsigned short* __restrict__ eW1t,
                                              const float* __restrict__ eb1,
                                              const unsigned short* __restrict__ eW2t,
                                              const float* __restrict__ eb2,
                                              const float4* __restrict__ alphab,
                                              void* __restrict__ zbuf) {
    __shared__ __align__(16) unsigned short nb1[4][16 * 64];
    const int tid = threadIdx.x;
    const int w = tid >> 6, lane = tid & 63;
    const int g = lane >> 4, t = lane & 15;
    const int slotbase = startA[p * (N_NODES + 1) + v0];
    const int slotend  = startA[p * (N_NODES + 1) + v1];
    const int j0 = slotbase + blockIdx.x * TE + w * 4;
    if (j0 >= slotend) return;
    const int ko = g * 8;

    // A-side: lane supplies MFMA A-row t -> slot j0+(t>>2), head t&3
    const int jA = min(j0 + (t >> 2), slotend - 1);
    const int eA = idxA[p * E_EDGES + jA];
    const int head = t & 3;
    const float* bA = proj + (size_t)ei[rA * E_EDGES + eA] * 256 + head * 64;
    const float* bB = proj + (size_t)ei[rB * E_EDGES + eA] * 256 + head * 64;
    short8 A0[2], A1[2];
#pragma unroll
    for (int ks = 0; ks < 2; ++ks) {
        A0[ks] = ldA(bA + ks * 32 + ko);
        A1[ks] = ldA(bB + ks * 32 + ko);
    }

    // C-side: lane outputs slot j0+g
    const int jC = j0 + g;
    const bool cvalid = (jC < slotend);
    const int eC = idxA[p * E_EDGES + min(jC, slotend - 1)];
    const float4 al = alphab[eC];
    const float alpha[4] = {al.x, al.y, al.z, al.w};

    float eb1c[4], eb2c[4];
#pragma unroll
    for (int f = 0; f < 4; ++f) { eb1c[f] = eb1[16 * f + t]; eb2c[f] = eb2[16 * f + t]; }

    f32x4 a2[4];
    pair_mlp(A0, A1, eW1t, eW2t, eb1c, &nb1[w][0], g, t, ko, a2);
    if (!cvalid) return;

    if (LAYER == 0) {
        unsigned short* zr = (unsigned short*)zbuf
                           + ((size_t)(jC - slotbase)) * 256 + t * 16;
        short8 lo, hi;
#pragma unroll
        for (int j = 0; j < 8; ++j) {
            int r = j >> 2, f = j & 3;
            lo[j] = (short)f2bf(alpha[r] * (a2[f][r] + eb2c[f]));
        }
#pragma unroll
        for (int j = 0; j < 8; ++j) {
            int r = 2 + (j >> 2), f = j & 3;
            hi[j] = (short)f2bf(alpha[r] * (a2[f][r] + eb2c[f]));
        }
        *(short8*)zr = lo;
        *(short8*)(zr + 8) = hi;
    } else {
        float* zr = (float*)zbuf + (size_t)jC * 64;   // slotbase==0 for layer 1
#pragma unroll
        for (int f = 0; f < 4; ++f) {
            float s = 0.f;
#pragma unroll
            for (int r = 0; r < 4; ++r) s += alpha[r] * (a2[f][r] + eb2c[f]);
            zr[16 * f + t] = 0.25f * s;
        }
    }
}

// ---------------------------------------------------------------------------
// reduce0: for node v in [v0,v1): x1[(p*N+v)*256+L] =
//   sigmoid(theta0[L]*proj0[v][L]+bias0[L] + sum over CSR slots of z0).
// One wave per node; contiguous z0 reads; stored->logical col mapping
// L = 64*(l&3) + 16*k + (l>>2)  for stored pos s = 4l+k.
// ---------------------------------------------------------------------------
__global__ __launch_bounds__(256) void reduce0_k(const unsigned short* __restrict__ z0,
                                                 const int* __restrict__ startA,
                                                 int p, int v0, int v1,
                                                 const float* __restrict__ proj0,
                                                 const float* __restrict__ theta,
                                                 const float* __restrict__ bias,
                                                 float* __restrict__ x1) {
    const int w = threadIdx.x >> 6, l = threadIdx.x & 63;
    const int v = v0 + blockIdx.x * 4 + w;
    if (v >= v1) return;
    const int slotbase = startA[p * (N_NODES + 1) + v0];
    const int s = startA[p * (N_NODES + 1) + v];
    const int e_ = startA[p * (N_NODES + 1) + v + 1];
    float acc[4] = {0.f, 0.f, 0.f, 0.f};
    for (int j = s; j < e_; ++j) {
        ushort4 u = *(const ushort4*)(z0 + ((size_t)(j - slotbase)) * 256 + l * 4);
        acc[0] += bf2f(u.x); acc[1] += bf2f(u.y);
        acc[2] += bf2f(u.z); acc[3] += bf2f(u.w);
    }
#pragma unroll
    for (int k = 0; k < 4; ++k) {
        const int L = 64 * (l & 3) + 16 * k + (l >> 2);
        float base = theta[L] * proj0[(size_t)v * 256 + L] + bias[L];
        float val = base + acc[k];
        x1[((size_t)(p * N_NODES + v)) * 256 + L] = 1.f / (1.f + expf(-val));
    }
}

// ---------------------------------------------------------------------------
// reduce1: out[(p*M1+v)*64+c] = 0.25*sum_h theta1*proj1 + bias1 + sum z1.
// 16 threads per row; contiguous z1 reads; v in [0,M1), edges only for v<N.
// ---------------------------------------------------------------------------
__global__ __launch_bounds__(256) void reduce1_k(const float* __restrict__ z1,
                                                 const int* __restrict__ startA,
                                                 int p,
                                                 const float* __restrict__ proj1,
                                                 const float* __restrict__ theta,
                                                 const float* __restrict__ bias,
                                                 float* __restrict__ out) {
    const int gid = blockIdx.x * 256 + threadIdx.x;
    if (gid >= M1 * 16) return;
    const int v = gid >> 4, c4 = gid & 15;
    float4 acc = make_float4(0.f, 0.f, 0.f, 0.f);
    if (v < N_NODES) {
        const int s = startA[p * (N_NODES + 1) + v];
        const int e_ = startA[p * (N_NODES + 1) + v + 1];
        for (int j = s; j < e_; ++j) {
            float4 u = *(const float4*)(z1 + (size_t)j * 64 + c4 * 4);
            acc.x += u.x; acc.y += u.y; acc.z += u.z; acc.w += u.w;
        }
    }
    float o[4] = {acc.x, acc.y, acc.z, acc.w};
#pragma unroll
    for (int c = 0; c < 4; ++c) {
        const int col = c4 * 4 + c;
        float b = 0.f;
#pragma unroll
        for (int h = 0; h < 4; ++h)
            b += theta[h * 64 + col] * proj1[(size_t)v * 256 + h * 64 + col];
        o[c] += 0.25f * b + bias[col];
    }
    *(float4*)(out + ((size_t)(p * M1 + v)) * 64 + c4 * 4) =
        make_float4(o[0], o[1], o[2], o[3]);
}

// ---------------------------------------------------------------------------
extern "C" void kernel_launch(void* const* d_in, const int* in_sizes, int n_in,
                              void* d_out, int out_size, void* d_ws, size_t ws_size,
                              hipStream_t stream) {
    (void)in_sizes; (void)n_in; (void)out_size; (void)ws_size;
    const float* x0       = (const float*)d_in[0];
    const int* ei         = (const int*)d_in[1];
    const float* p0_Wp    = (const float*)d_in[2];
    const float* p0_aW1   = (const float*)d_in[3];
    const float* p0_ab1   = (const float*)d_in[4];
    const float* p0_aW2   = (const float*)d_in[5];
    const float* p0_ab2   = (const float*)d_in[6];
    const float* p0_eW1   = (const float*)d_in[7];
    const float* p0_eb1   = (const float*)d_in[8];
    const float* p0_eW2   = (const float*)d_in[9];
    const float* p0_eb2   = (const float*)d_in[10];
    const float* p0_theta = (const float*)d_in[11];
    const float* p0_bias  = (const float*)d_in[12];
    const float* p1_Wp    = (const float*)d_in[13];
    const float* p1_aW1   = (const float*)d_in[14];
    const float* p1_ab1   = (const float*)d_in[15];
    const float* p1_aW2   = (const float*)d_in[16];
    const float* p1_ab2   = (const float*)d_in[17];
    const float* p1_eW1   = (const float*)d_in[18];
    const float* p1_eb1   = (const float*)d_in[19];
    const float* p1_eW2   = (const float*)d_in[20];
    const float* p1_eb2   = (const float*)d_in[21];
    const float* p1_theta = (const float*)d_in[22];
    const float* p1_bias  = (const float*)d_in[23];

    // Workspace map (floats; total 32,324,580 f = 129.3 MB <= proven 146.6):
    //  seg1 [0 .. 15.36M):   proj0 (first 5.12M, layer0) / proj1 (full, layer1)
    //                        z0 chunk overlays [5.12M..15.36M) as bf16 (80000 slots)
    //  seg2 [15.36M..30.72M): x1 (layer0 out / layer1 gemm in); z1 overlays after
    //  seg3 [30.72M..):      bf16 weights, CSR (cnt/startA/cursor/idxA), alpha
    float* ws = (float*)d_ws;
    float* proj0 = ws;
    float* proj1 = ws;
    unsigned short* z0 = (unsigned short*)(ws + 5120000);   // 20.48M bf16
    float* x1 = ws + 15360000;
    float* z1 = x1;                                         // overlays dead x1
    unsigned short* wt = (unsigned short*)(ws + 30720000);  // 49,152 bf16
    unsigned short* w0a  = wt;               // aW1^T 64x192
    unsigned short* w0e1 = wt + 12288;       // eW1^T 64x128
    unsigned short* w0e2 = wt + 20480;       // eW2^T 64x64
    unsigned short* w1a  = wt + 24576;
    unsigned short* w1e1 = wt + 36864;
    unsigned short* w1e2 = wt + 45056;
    int* cnt    = (int*)(ws + 30744576);     // 60,000
    int* startA = cnt + 60000;               // 60,003
    int* cursor = startA + 60003;            // 60,000
    int* idxA   = cursor + 60000;            // 600,000  (ends 31,524,579)
    float4* alphab = (float4*)(ws + 31524580);  // 800,000 f, 16B-aligned
    float* out = (float*)d_out;

    const int EB = E_EDGES / TE;             // 12500
    // layer-0 node chunks (slots/chunk ~66.7K << Z0CAP=80000)
    const int CH0[4] = {0, 6667, 13334, 20000};
    const int roleA[3] = {1, 0, 0};          // p0=(m,s) p1=(d,s) p2=(d,m)
    const int roleB[3] = {2, 2, 1};

    // ---- weight prep (bf16 transposes) ----
    prep_wt<<<(64 * 192 + 255) / 256, 256, 0, stream>>>(p0_aW1, w0a, 192);
    prep_wt<<<(64 * 128 + 255) / 256, 256, 0, stream>>>(p0_eW1, w0e1, 128);
    prep_wt<<<(64 * 64 + 255) / 256, 256, 0, stream>>>(p0_eW2, w0e2, 64);
    prep_wt<<<(64 * 192 + 255) / 256, 256, 0, stream>>>(p1_aW1, w1a, 192);
    prep_wt<<<(64 * 128 + 255) / 256, 256, 0, stream>>>(p1_eW1, w1e1, 128);
    prep_wt<<<(64 * 64 + 255) / 256, 256, 0, stream>>>(p1_eW2, w1e2, 64);

    // ---- CSR (shared by both layers) ----
    zero_cnt<<<(3 * N_NODES + 255) / 256, 256, 0, stream>>>(cnt);
    hist_k<<<(3 * E_EDGES + 255) / 256, 256, 0, stream>>>(ei, cnt);
    scan_k<<<3, 1024, 0, stream>>>(cnt, startA, cursor);
    fill_k<<<(3 * E_EDGES + 255) / 256, 256, 0, stream>>>(ei, cursor, idxA);

    // ---- layer 0 ----
    gemm_proj<64><<<N_NODES / 16, 256, 0, stream>>>(x0, p0_Wp, proj0);
    att_alpha<<<EB, 256, 0, stream>>>(proj0, ei, w0a, p0_ab1, p0_aW2, p0_ab2, alphab);
    for (int p = 0; p < 3; ++p) {
        for (int c = 0; c < 3; ++c) {
            pair_k<0><<<Z0CAP / TE, 256, 0, stream>>>(proj0, ei, idxA, startA,
                                                      p, roleA[p], roleB[p],
                                                      CH0[c], CH0[c + 1],
                                                      w0e1, p0_eb1, w0e2, p0_eb2,
                                                      alphab, (void*)z0);
            reduce0_k<<<(CH0[c + 1] - CH0[c] + 3) / 4, 256, 0, stream>>>(z0, startA,
                                                      p, CH0[c], CH0[c + 1],
                                                      proj0, p0_theta, p0_bias, x1);
        }
    }

    // ---- layer 1 ----
    gemm_proj<256><<<M1 / 16, 256, 0, stream>>>(x1, p1_Wp, proj1);
    att_alpha<<<EB, 256, 0, stream>>>(proj1, ei, w1a, p1_ab1, p1_aW2, p1_ab2, alphab);
    for (int p = 0; p < 3; ++p) {
        pair_k<1><<<EB, 256, 0, stream>>>(proj1, ei, idxA, startA,
                                          p, roleA[p], roleB[p], 0, N_NODES,
                                          w1e1, p1_eb1, w1e2, p1_eb2,
                                          alphab, (void*)z1);
        reduce1_k<<<(M1 * 16 + 255) / 256, 256, 0, stream>>>(z1, startA, p,
                                                             proj1, p1_theta,
                                                             p1_bias, out);
    }
}

// Round 8
// 1073.060 us; speedup vs baseline: 1.8238x; 1.8238x over previous
//
#include <hip/hip_runtime.h>
#include <math.h>

#define N_NODES 20000
#define E_EDGES 200000
#define M1 60000            // layer-1 node count (3*N)
#define TE 16               // edges per block in fused kernel

typedef __attribute__((ext_vector_type(8))) short short8;
typedef __attribute__((ext_vector_type(4))) float f32x4;

// float -> bf16 (round-to-nearest-even), bit-level
__device__ __forceinline__ unsigned short f2bf(float f) {
    union { float f; unsigned int u; } v; v.f = f;
    unsigned int r = v.u + 0x7fffu + ((v.u >> 16) & 1u);
    return (unsigned short)(r >> 16);
}
__device__ __forceinline__ float bf2f(unsigned short u) {
    union { unsigned int u; float f; } v; v.u = ((unsigned int)u) << 16;
    return v.f;
}

// packed bf16 atomic add (2 adjacent bf16 elements, 4B-aligned address)
__device__ __forceinline__ void atom_pk_bf16(unsigned short* p, float lo, float hi) {
    unsigned int pk = (unsigned int)f2bf(lo) | ((unsigned int)f2bf(hi) << 16);
    asm volatile("global_atomic_pk_add_bf16 %0, %1, off" :: "v"(p), "v"(pk) : "memory");
}

// ---------------------------------------------------------------------------
// GEMM: C[M,256] = X[M,K] @ W[K,256]  (fp32 compute, fp32 + bf16 outputs)
// ---------------------------------------------------------------------------
template<int K>
__global__ __launch_bounds__(256) void gemm_proj(const float* __restrict__ X,
                                                 const float* __restrict__ W,
                                                 float* __restrict__ C,
                                                 unsigned short* __restrict__ Ch) {
    __shared__ float Xs[16][K];
    const int row0 = blockIdx.x * 16;
    const int tid = threadIdx.x;
    for (int i4 = tid; i4 < 16 * K / 4; i4 += 256) {
        int r = i4 / (K / 4), kq = i4 - r * (K / 4);
        ((float4*)&Xs[r][0])[kq] = ((const float4*)(X + (size_t)(row0 + r) * K))[kq];
    }
    __syncthreads();
    const int rg = tid >> 6;
    const int j0 = (tid & 63) * 4;
    float acc[4][4];
#pragma unroll
    for (int r = 0; r < 4; ++r)
#pragma unroll
        for (int t = 0; t < 4; ++t) acc[r][t] = 0.f;
#pragma unroll 4
    for (int k = 0; k < K; ++k) {
        float4 wq = *(const float4*)(W + (size_t)k * 256 + j0);
#pragma unroll
        for (int r = 0; r < 4; ++r) {
            float xv = Xs[rg * 4 + r][k];
            acc[r][0] = fmaf(xv, wq.x, acc[r][0]);
            acc[r][1] = fmaf(xv, wq.y, acc[r][1]);
            acc[r][2] = fmaf(xv, wq.z, acc[r][2]);
            acc[r][3] = fmaf(xv, wq.w, acc[r][3]);
        }
    }
#pragma unroll
    for (int r = 0; r < 4; ++r) {
        const size_t base = (size_t)(row0 + rg * 4 + r) * 256 + j0;
        *(float4*)(C + base) = make_float4(acc[r][0], acc[r][1], acc[r][2], acc[r][3]);
        ushort4 h;
        h.x = f2bf(acc[r][0]); h.y = f2bf(acc[r][1]);
        h.z = f2bf(acc[r][2]); h.w = f2bf(acc[r][3]);
        *(ushort4*)(Ch + base) = h;
    }
}

// ---------------------------------------------------------------------------
// MFMA GEMM: C[M1,256] = A[M1,256](bf16) @ B, BT[n][k] pre-transposed bf16.
// Block: 4 waves x 16 rows = 64 rows; wave covers all 256 cols (16 n-frags).
// ---------------------------------------------------------------------------
__global__ __launch_bounds__(256) void gemm_mfma(const unsigned short* __restrict__ A,
                                                 const unsigned short* __restrict__ BT,
                                                 float* __restrict__ C,
                                                 unsigned short* __restrict__ Ch) {
    const int tid = threadIdx.x;
    const int w = tid >> 6, lane = tid & 63;
    const int g = lane >> 4, t = lane & 15;
    const int rA = min(blockIdx.x * 64 + w * 16 + t, M1 - 1);
    const f32x4 z = {0.f, 0.f, 0.f, 0.f};
    f32x4 acc[16];
#pragma unroll
    for (int f = 0; f < 16; ++f) acc[f] = z;
#pragma unroll
    for (int ks = 0; ks < 8; ++ks) {
        short8 a = *(const short8*)(A + (size_t)rA * 256 + ks * 32 + g * 8);
#pragma unroll
        for (int f = 0; f < 16; ++f) {
            short8 b = *(const short8*)(BT + (size_t)(16 * f + t) * 256 + ks * 32 + g * 8);
            acc[f] = __builtin_amdgcn_mfma_f32_16x16x32_bf16(a, b, acc[f], 0, 0, 0);
        }
    }
    const int rC0 = blockIdx.x * 64 + w * 16 + 4 * g;
#pragma unroll
    for (int r = 0; r < 4; ++r) {
        const int row = rC0 + r;
        if (row < M1) {
#pragma unroll
            for (int f = 0; f < 16; ++f) {
                C[(size_t)row * 256 + 16 * f + t] = acc[f][r];
                Ch[(size_t)row * 256 + 16 * f + t] = f2bf(acc[f][r]);
            }
        }
    }
}

// ---------------------------------------------------------------------------
// Weight prep: W[K][64] fp32 -> WT[64][K] bf16 (transpose + convert)
// ---------------------------------------------------------------------------
__global__ void prep_wt(const float* __restrict__ W, unsigned short* __restrict__ WT,
                        int K) {
    int i = blockIdx.x * 256 + threadIdx.x;
    if (i >= 64 * K) return;
    int c = i / K, k = i - c * K;
    WT[i] = f2bf(W[k * 64 + c]);
}
// Wp1[256][256] -> WpT[256 out][256 k] bf16
__global__ void prep_wpt(const float* __restrict__ W, unsigned short* __restrict__ WT) {
    int i = blockIdx.x * 256 + threadIdx.x;
    if (i >= 256 * 256) return;
    int n = i >> 8, k = i & 255;
    WT[i] = f2bf(W[k * 256 + n]);
}

// ---------------------------------------------------------------------------
// x1b (bf16 accumulator) init: x1b[(p*N+v)*256+c] = bf16(theta0[c]*proj0+bias0[c])
// ---------------------------------------------------------------------------
__global__ void init_x1b(const float* __restrict__ proj0,
                         const float* __restrict__ theta,
                         const float* __restrict__ bias,
                         unsigned int* __restrict__ x1b) {  // as u32 pairs
    int gid = blockIdx.x * 256 + threadIdx.x;               // over N*128
    if (gid >= N_NODES * 128) return;
    int v = gid >> 7, c2 = gid & 127;
    int c = c2 * 2;
    float lo = theta[c] * proj0[(size_t)v * 256 + c] + bias[c];
    float hi = theta[c + 1] * proj0[(size_t)v * 256 + c + 1] + bias[c + 1];
    unsigned int pk = (unsigned int)f2bf(lo) | ((unsigned int)f2bf(hi) << 16);
    x1b[(size_t)v * 128 + c2] = pk;
    x1b[(size_t)(N_NODES + v) * 128 + c2] = pk;
    x1b[(size_t)(2 * N_NODES + v) * 128 + c2] = pk;
}

// in-place bf16 sigmoid over x1b (after edge accumulation)
__global__ void sigmoid_x1b(unsigned int* __restrict__ x1b) {
    int gid = blockIdx.x * 256 + threadIdx.x;               // over 3N*128
    if (gid >= M1 * 128) return;
    unsigned int u = x1b[gid];
    float lo = 1.f / (1.f + expf(-bf2f((unsigned short)(u & 0xffffu))));
    float hi = 1.f / (1.f + expf(-bf2f((unsigned short)(u >> 16))));
    x1b[gid] = (unsigned int)f2bf(lo) | ((unsigned int)f2bf(hi) << 16);
}

__global__ void zero_zacc(unsigned int* __restrict__ z, int n) {
    int gid = blockIdx.x * 256 + threadIdx.x;
    if (gid < n) z[gid] = 0u;
}

// ---------------------------------------------------------------------------
// final: out[(p*M1+v)*64+c] = 0.25*sum_h theta1*proj1 + bias1[c] + zacc
// ---------------------------------------------------------------------------
__global__ void final_out(const float* __restrict__ proj1,
                          const unsigned short* __restrict__ zacc,
                          const float* __restrict__ theta,
                          const float* __restrict__ bias,
                          float* __restrict__ out) {
    int gid = blockIdx.x * 256 + threadIdx.x;               // over M1*64
    if (gid >= M1 * 64) return;
    int v = gid >> 6, c = gid & 63;
    float b = 0.f;
#pragma unroll
    for (int h = 0; h < 4; ++h)
        b += theta[h * 64 + c] * proj1[(size_t)v * 256 + h * 64 + c];
    float base = 0.25f * b + bias[c];
#pragma unroll
    for (int p = 0; p < 3; ++p) {
        size_t idx = (size_t)(p * M1 + v) * 64 + c;
        out[idx] = base + bf2f(zacc[idx]);
    }
}

// ---------------------------------------------------------------------------
// Pair MLP core: a1 = leaky(concat(A0,A1)@eW1+eb1); a2 = a1@eW2.
// nb: per-wave LDS scratch, XOR-chunk-swizzled bf16.
// ---------------------------------------------------------------------------
__device__ __forceinline__ void pair_mlp(const short8 A0[2], const short8 A1[2],
                                         const unsigned short* __restrict__ eW1t,
                                         const unsigned short* __restrict__ eW2t,
                                         const float eb1c[4],
                                         unsigned short* nb,
                                         int g, int t, int ko, f32x4 a2[4]) {
    const f32x4 z = {0.f, 0.f, 0.f, 0.f};
    f32x4 a1[4] = {z, z, z, z};
#pragma unroll
    for (int half = 0; half < 2; ++half) {
#pragma unroll
        for (int ks = 0; ks < 2; ++ks) {
            short8 a = half ? A1[ks] : A0[ks];
#pragma unroll
            for (int f = 0; f < 4; ++f) {
                short8 b = *(const short8*)(eW1t + (16 * f + t) * 128 + half * 64 + ks * 32 + ko);
                a1[f] = __builtin_amdgcn_mfma_f32_16x16x32_bf16(a, b, a1[f], 0, 0, 0);
            }
        }
    }
#pragma unroll
    for (int f = 0; f < 4; ++f) {
        const int col = 16 * f + t;
#pragma unroll
        for (int r = 0; r < 4; ++r) {
            const int row = 4 * g + r;
            float hv = a1[f][r] + eb1c[f];
            hv = (hv >= 0.f) ? hv : 0.2f * hv;
            const int chunk = (col >> 3) ^ (row & 7);
            nb[row * 64 + chunk * 8 + (col & 7)] = f2bf(hv);
        }
    }
#pragma unroll
    for (int f = 0; f < 4; ++f) a2[f] = z;
#pragma unroll
    for (int ks = 0; ks < 2; ++ks) {
        const int chunk = (ks * 4 + g) ^ (t & 7);
        short8 a = *(const short8*)(nb + t * 64 + chunk * 8);
#pragma unroll
        for (int f = 0; f < 4; ++f) {
            short8 b = *(const short8*)(eW2t + (16 * f + t) * 64 + ks * 32 + ko);
            a2[f] = __builtin_amdgcn_mfma_f32_16x16x32_bf16(a, b, a2[f], 0, 0, 0);
        }
    }
}

// pair + pk-bf16 atomic scatter
template<int LAYER>
__device__ __forceinline__ void do_pair(int p,
                                        const short8 A0[2], const short8 A1[2],
                                        const unsigned short* __restrict__ eW1t,
                                        const unsigned short* __restrict__ eW2t,
                                        const float eb1c[4], const float eb2c[4],
                                        const float alpha[4],
                                        unsigned short* nb,
                                        int g, int t, int ko, int vtp,
                                        unsigned short* __restrict__ accb) {
    f32x4 a2[4];
    pair_mlp(A0, A1, eW1t, eW2t, eb1c, nb, g, t, ko, a2);
    if (LAYER == 0) {
        unsigned short* dst = accb + ((size_t)(p * N_NODES + vtp)) * 256;
#pragma unroll
        for (int f = 0; f < 4; ++f) {
#pragma unroll
            for (int r = 0; r < 4; ++r) {
                float val = alpha[r] * (a2[f][r] + eb2c[f]);
                float pv = __shfl_xor(val, 1);
                if (!(t & 1))
                    atom_pk_bf16(dst + r * 64 + 16 * f + t, val, pv);
            }
        }
    } else {
        unsigned short* dst = accb + ((size_t)(p * M1 + vtp)) * 64;
#pragma unroll
        for (int f = 0; f < 4; ++f) {
            float s = 0.f;
#pragma unroll
            for (int r = 0; r < 4; ++r) s += alpha[r] * (a2[f][r] + eb2c[f]);
            s *= 0.25f;
            float pv = __shfl_xor(s, 1);
            if (!(t & 1))
                atom_pk_bf16(dst + 16 * f + t, s, pv);
        }
    }
}

// ---------------------------------------------------------------------------
// Fused edge kernel (MFMA). Block: 16 edges, 4 waves; wave = 4 edges = 16 rows.
// Gathers bf16 proj rows once; att + softmax + 3 pair MLPs + pk-bf16 scatter.
// ---------------------------------------------------------------------------
template<int LAYER>
__global__ __launch_bounds__(256) void fused_edge(const unsigned short* __restrict__ projh,
                                                  const int* __restrict__ ei,
                                                  const unsigned short* __restrict__ aW1t,
                                                  const float* __restrict__ ab1,
                                                  const float* __restrict__ aW2,
                                                  const float* __restrict__ ab2,
                                                  const unsigned short* __restrict__ eW1t,
                                                  const float* __restrict__ eb1,
                                                  const unsigned short* __restrict__ eW2t,
                                                  const float* __restrict__ eb2,
                                                  unsigned short* __restrict__ accb) {
    __shared__ __align__(16) unsigned short nb1[4][16 * 64];

    const int tid = threadIdx.x;
    const int w = tid >> 6, lane = tid & 63;
    const int g = lane >> 4, t = lane & 15;
    const int e0 = blockIdx.x * TE + w * 4;
    const int ko = g * 8;

    const int ea = e0 + (t >> 2);
    const int head = t & 3;
    const unsigned short* bD = projh + (size_t)ei[ea] * 256 + head * 64;
    const unsigned short* bM = projh + (size_t)ei[E_EDGES + ea] * 256 + head * 64;
    const unsigned short* bS = projh + (size_t)ei[2 * E_EDGES + ea] * 256 + head * 64;

    const int ec = e0 + g;
    const int vt0 = ei[ec], vt1 = ei[E_EDGES + ec], vt2 = ei[2 * E_EDGES + ec];

    short8 aD[2], aM[2], aS[2];
#pragma unroll
    for (int ks = 0; ks < 2; ++ks) {
        aD[ks] = *(const short8*)(bD + ks * 32 + ko);
        aM[ks] = *(const short8*)(bM + ks * 32 + ko);
        aS[ks] = *(const short8*)(bS + ks * 32 + ko);
    }

    float ab1c[4], aW2c[4], eb1c[4], eb2c[4];
#pragma unroll
    for (int f = 0; f < 4; ++f) {
        ab1c[f] = ab1[16 * f + t];
        aW2c[f] = aW2[16 * f + t];
        eb1c[f] = eb1[16 * f + t];
        eb2c[f] = eb2[16 * f + t];
    }

    // ---- attention MLP: H = [d|m|s] @ aW1  (K=192) ----
    const f32x4 z = {0.f, 0.f, 0.f, 0.f};
    f32x4 acc[4] = {z, z, z, z};
#pragma unroll
    for (int ks = 0; ks < 2; ++ks) {
        short8 a = aD[ks];
#pragma unroll
        for (int f = 0; f < 4; ++f) {
            short8 b = *(const short8*)(aW1t + (16 * f + t) * 192 + 0 * 64 + ks * 32 + ko);
            acc[f] = __builtin_amdgcn_mfma_f32_16x16x32_bf16(a, b, acc[f], 0, 0, 0);
        }
    }
#pragma unroll
    for (int ks = 0; ks < 2; ++ks) {
        short8 a = aM[ks];
#pragma unroll
        for (int f = 0; f < 4; ++f) {
            short8 b = *(const short8*)(aW1t + (16 * f + t) * 192 + 1 * 64 + ks * 32 + ko);
            acc[f] = __builtin_amdgcn_mfma_f32_16x16x32_bf16(a, b, acc[f], 0, 0, 0);
        }
    }
#pragma unroll
    for (int ks = 0; ks < 2; ++ks) {
        short8 a = aS[ks];
#pragma unroll
        for (int f = 0; f < 4; ++f) {
            short8 b = *(const short8*)(aW1t + (16 * f + t) * 192 + 2 * 64 + ks * 32 + ko);
            acc[f] = __builtin_amdgcn_mfma_f32_16x16x32_bf16(a, b, acc[f], 0, 0, 0);
        }
    }

    // ---- score epilogue: relu, @aW2 (col-reduce), +ab2, leaky, softmax ----
    float alpha[4];
    {
        float p_[4];
#pragma unroll
        for (int r = 0; r < 4; ++r) {
            float s = 0.f;
#pragma unroll
            for (int f = 0; f < 4; ++f) {
                float hv = fmaxf(acc[f][r] + ab1c[f], 0.f);
                s = fmaf(hv, aW2c[f], s);
            }
            p_[r] = s;
        }
#pragma unroll
        for (int off = 1; off < 16; off <<= 1) {
#pragma unroll
            for (int r = 0; r < 4; ++r) p_[r] += __shfl_xor(p_[r], off);
        }
        const float b2 = ab2[0];
        float sc[4];
#pragma unroll
        for (int r = 0; r < 4; ++r) {
            float v = p_[r] + b2;
            sc[r] = (v >= 0.f) ? v : 0.2f * v;
        }
        float mx = fmaxf(fmaxf(sc[0], sc[1]), fmaxf(sc[2], sc[3]));
        float ex[4], sum = 0.f;
#pragma unroll
        for (int r = 0; r < 4; ++r) { ex[r] = expf(sc[r] - mx); sum += ex[r]; }
        float inv = 1.f / sum;
#pragma unroll
        for (int r = 0; r < 4; ++r) alpha[r] = ex[r] * inv;
    }

    // ---- 3 pair MLPs + scatter (p0=(m,s)->d, p1=(d,s)->m, p2=(d,m)->s) ----
    unsigned short* nb = &nb1[w][0];
    do_pair<LAYER>(0, aM, aS, eW1t, eW2t, eb1c, eb2c, alpha, nb, g, t, ko, vt0, accb);
    do_pair<LAYER>(1, aD, aS, eW1t, eW2t, eb1c, eb2c, alpha, nb, g, t, ko, vt1, accb);
    do_pair<LAYER>(2, aD, aM, eW1t, eW2t, eb1c, eb2c, alpha, nb, g, t, ko, vt2, accb);
}

// ---------------------------------------------------------------------------
extern "C" void kernel_launch(void* const* d_in, const int* in_sizes, int n_in,
                              void* d_out, int out_size, void* d_ws, size_t ws_size,
                              hipStream_t stream) {
    (void)in_sizes; (void)n_in; (void)out_size; (void)ws_size;
    const float* x0       = (const float*)d_in[0];
    const int* ei         = (const int*)d_in[1];
    const float* p0_Wp    = (const float*)d_in[2];
    const float* p0_aW1   = (const float*)d_in[3];
    const float* p0_ab1   = (const float*)d_in[4];
    const float* p0_aW2   = (const float*)d_in[5];
    const float* p0_ab2   = (const float*)d_in[6];
    const float* p0_eW1   = (const float*)d_in[7];
    const float* p0_eb1   = (const float*)d_in[8];
    const float* p0_eW2   = (const float*)d_in[9];
    const float* p0_eb2   = (const float*)d_in[10];
    const float* p0_theta = (const float*)d_in[11];
    const float* p0_bias  = (const float*)d_in[12];
    const float* p1_Wp    = (const float*)d_in[13];
    const float* p1_aW1   = (const float*)d_in[14];
    const float* p1_ab1   = (const float*)d_in[15];
    const float* p1_aW2   = (const float*)d_in[16];
    const float* p1_ab2   = (const float*)d_in[17];
    const float* p1_eW1   = (const float*)d_in[18];
    const float* p1_eb1   = (const float*)d_in[19];
    const float* p1_eW2   = (const float*)d_in[20];
    const float* p1_eb2   = (const float*)d_in[21];
    const float* p1_theta = (const float*)d_in[22];
    const float* p1_bias  = (const float*)d_in[23];

    // Workspace (floats; total 36,537,344 f = 146.15 MB <= proven 146.56):
    //  [0, 15.36M):          proj1 fp32 (layer1).  During layer0 this region
    //                        holds proj0 fp32 [0,5.12M) + projh0 bf16 [5.12M,7.68M)
    //                        (both dead before gemm_mfma writes proj1).
    //  [15.36M, 23.04M):     x1b  bf16 accumulator (3N x 256)
    //  [23.04M, 30.72M):     projh1 bf16 (3N x 256)
    //  [30.72M, 36.48M):     zacc bf16 accumulator (3*M1 x 64)
    //  [36.48M, ...):        bf16 weights (49,152) + WpT1 (65,536)
    float* ws = (float*)d_ws;
    float* proj0 = ws;
    unsigned short* projh0 = (unsigned short*)(ws + 5120000);
    float* proj1 = ws;
    unsigned short* x1b    = (unsigned short*)(ws + 15360000);
    unsigned short* projh1 = (unsigned short*)(ws + 23040000);
    unsigned short* zacc   = (unsigned short*)(ws + 30720000);
    unsigned short* wt     = (unsigned short*)(ws + 36480000);
    unsigned short* w0a  = wt;               // aW1^T 64x192
    unsigned short* w0e1 = wt + 12288;       // eW1^T 64x128
    unsigned short* w0e2 = wt + 20480;       // eW2^T 64x64
    unsigned short* w1a  = wt + 24576;
    unsigned short* w1e1 = wt + 36864;
    unsigned short* w1e2 = wt + 45056;
    unsigned short* wpT1 = wt + 49152;       // Wp1^T 256x256
    float* out = (float*)d_out;

    const int EB = E_EDGES / TE;             // 12500

    // ---- weight prep ----
    prep_wt<<<(64 * 192 + 255) / 256, 256, 0, stream>>>(p0_aW1, w0a, 192);
    prep_wt<<<(64 * 128 + 255) / 256, 256, 0, stream>>>(p0_eW1, w0e1, 128);
    prep_wt<<<(64 * 64 + 255) / 256, 256, 0, stream>>>(p0_eW2, w0e2, 64);
    prep_wt<<<(64 * 192 + 255) / 256, 256, 0, stream>>>(p1_aW1, w1a, 192);
    prep_wt<<<(64 * 128 + 255) / 256, 256, 0, stream>>>(p1_eW1, w1e1, 128);
    prep_wt<<<(64 * 64 + 255) / 256, 256, 0, stream>>>(p1_eW2, w1e2, 64);
    prep_wpt<<<(256 * 256 + 255) / 256, 256, 0, stream>>>(p1_Wp, wpT1);

    // ---- layer 0 ----
    gemm_proj<64><<<N_NODES / 16, 256, 0, stream>>>(x0, p0_Wp, proj0, projh0);
    init_x1b<<<(N_NODES * 128 + 255) / 256, 256, 0, stream>>>(proj0, p0_theta, p0_bias,
                                                              (unsigned int*)x1b);
    fused_edge<0><<<EB, 256, 0, stream>>>(projh0, ei, w0a, p0_ab1, p0_aW2, p0_ab2,
                                          w0e1, p0_eb1, w0e2, p0_eb2, x1b);
    sigmoid_x1b<<<(M1 * 128 + 255) / 256, 256, 0, stream>>>((unsigned int*)x1b);

    // ---- layer 1 ----
    gemm_mfma<<<(M1 + 63) / 64, 256, 0, stream>>>(x1b, wpT1, proj1, projh1);
    zero_zacc<<<(3 * M1 * 32 + 255) / 256, 256, 0, stream>>>((unsigned int*)zacc,
                                                             3 * M1 * 32);
    fused_edge<1><<<EB, 256, 0, stream>>>(projh1, ei, w1a, p1_ab1, p1_aW2, p1_ab2,
                                          w1e1, p1_eb1, w1e2, p1_eb2, zacc);
    final_out<<<(M1 * 64 + 255) / 256, 256, 0, stream>>>(proj1, zacc, p1_theta,
                                                         p1_bias, out);
}